// Round 13
// baseline (78.490 us; speedup 1.0000x reference)
//
#include <hip/hip_runtime.h>

#define KFEAT 32
#define NB 8            // batch elements per block (MLP kernel)
#define XPITCH 544      // floats per element row in xs (8 chunks * 68)
#define APITCH 272      // floats per bag row in accs overlay (= XPITCH/2)

__device__ __forceinline__ float clip01(float v) {
    return fminf(fmaxf(v, 0.0f), 1.0f);
}

// ---- one-pass per-row absmax + int8 quantize (one wave per row) ----
__global__ __launch_bounds__(256) void quantize_table_i8(
    const float* __restrict__ src, uint* __restrict__ qt,
    float* __restrict__ scales, int nrows)
{
    const int row = blockIdx.x * 4 + (threadIdx.x >> 6);
    const int l   = threadIdx.x & 63;
    if (row >= nrows) return;

    const float4 v = reinterpret_cast<const float4*>(src)[(size_t)row * 64 + l];
    float m = fmaxf(fmaxf(fabsf(v.x), fabsf(v.y)), fmaxf(fabsf(v.z), fabsf(v.w)));
    m = fmaxf(m, __shfl_xor(m, 1));
    m = fmaxf(m, __shfl_xor(m, 2));
    m = fmaxf(m, __shfl_xor(m, 4));
    m = fmaxf(m, __shfl_xor(m, 8));
    m = fmaxf(m, __shfl_xor(m, 16));
    m = fmaxf(m, __shfl_xor(m, 32));

    const float inv = (m > 0.0f) ? 127.0f / m : 0.0f;
    const int b0 = ((int)rintf(v.x * inv)) & 0xFF;
    const int b1 = ((int)rintf(v.y * inv)) & 0xFF;
    const int b2 = ((int)rintf(v.z * inv)) & 0xFF;
    const int b3 = ((int)rintf(v.w * inv)) & 0xFF;
    qt[(size_t)row * 64 + l] = (uint)b0 | ((uint)b1 << 8) | ((uint)b2 << 16) | ((uint)b3 << 24);
    if (l == 0) scales[row] = m * (1.0f / 127.0f);
}

// ---------------- k2: pure gather. One wave per bag, no LDS, no barriers. ----------------
// bag = 2*element + side; writes raw bag sum (256 floats) to accs[bag].
__global__ __launch_bounds__(256, 8) void gather_i8_kernel(
    const int* __restrict__ wf, const int* __restrict__ bf,
    const uint* __restrict__ qt, const float* __restrict__ scales,
    float* __restrict__ accs)
{
    const int t    = threadIdx.x;
    const int l    = t & 63;
    const int w    = t >> 6;
    const int sub  = l & 31;
    const int bag  = blockIdx.x * 4 + w;
    const int e    = bag >> 1;
    const int side = bag & 1;
    const int* fp  = side ? bf : wf;

    const int iv = fp[(size_t)e * KFEAT + sub];
    float a0 = 0.f, a1 = 0.f, a2 = 0.f, a3 = 0.f;
    #pragma unroll
    for (int k = 0; k < KFEAT; ++k) {
        const int row  = __builtin_amdgcn_readlane(iv, k);   // SGPR-uniform base
        const int  q   = (int)qt[(size_t)row * 64 + l];
        const float sc = scales[row];                        // scalar load
        a0 = fmaf((float)((q << 24) >> 24), sc, a0);
        a1 = fmaf((float)((q << 16) >> 24), sc, a1);
        a2 = fmaf((float)((q <<  8) >> 24), sc, a2);
        a3 = fmaf((float)( q        >> 24), sc, a3);
    }
    *reinterpret_cast<float4*>(&accs[(size_t)bag * 256 + l * 4]) =
        make_float4(a0, a1, a2, a3);
}

// ---------------- k3: mix + MLP. Reads bag sums coalesced; B/C/D from R8. ----------------
__global__ __launch_bounds__(256, 8) void mlp_kernel(
    const float* __restrict__ accs, const float* __restrict__ stm,
    const float* __restrict__ ft_bias,
    const float* __restrict__ W1, const float* __restrict__ b1,
    const float* __restrict__ W2, const float* __restrict__ b2,
    const float* __restrict__ Wo, const float* __restrict__ bo,
    float* __restrict__ out)
{
    __shared__ float lds[NB * XPITCH];
    __shared__ float y1s[NB][32];

    const int t  = threadIdx.x;
    const int l  = t & 63;
    const int w  = t >> 6;
    const int b0 = blockIdx.x * NB;

    // ---- Phase A': stage 16 bag-sum rows (1KB each) into LDS, coalesced ----
    #pragma unroll
    for (int g = 0; g < 4; ++g) {
        const int lbag = g * 4 + w;          // 0..15, same layout Phase B expects
        const float4 v = *reinterpret_cast<const float4*>(
            &accs[((size_t)2 * b0 + lbag) * 256 + l * 4]);
        *reinterpret_cast<float4*>(&lds[lbag * APITCH + l * 4]) = v;
    }
    __syncthreads();

    // ---- Phase B: mix + clip, in-place overlay (read all -> barrier -> write) ----
    {
        const int e = t >> 5, r = t & 31;
        const float s  = stm[b0 + e];
        const float os = 1.0f - s;
        const float4 wa0 = *reinterpret_cast<const float4*>(&lds[(2 * e + 0) * APITCH + 4 * r]);
        const float4 ba0 = *reinterpret_cast<const float4*>(&lds[(2 * e + 1) * APITCH + 4 * r]);
        const float4 wa1 = *reinterpret_cast<const float4*>(&lds[(2 * e + 0) * APITCH + 4 * (r + 32)]);
        const float4 ba1 = *reinterpret_cast<const float4*>(&lds[(2 * e + 1) * APITCH + 4 * (r + 32)]);
        const float4 fb0 = reinterpret_cast<const float4*>(ft_bias)[r];
        const float4 fb1 = reinterpret_cast<const float4*>(ft_bias)[r + 32];
        __syncthreads();

        #define MIXW(wa, ba, fb, i, hf)                                              \
        {                                                                            \
            float4 xv;                                                               \
            if (hf == 0) {                                                           \
                xv.x = clip01(fmaf(s, (wa).x, fmaf(os, (ba).x, (fb).x)));            \
                xv.y = clip01(fmaf(s, (wa).y, fmaf(os, (ba).y, (fb).y)));            \
                xv.z = clip01(fmaf(s, (wa).z, fmaf(os, (ba).z, (fb).z)));            \
                xv.w = clip01(fmaf(s, (wa).w, fmaf(os, (ba).w, (fb).w)));            \
            } else {                                                                 \
                xv.x = clip01(fmaf(s, (ba).x, fmaf(os, (wa).x, (fb).x)));            \
                xv.y = clip01(fmaf(s, (ba).y, fmaf(os, (wa).y, (fb).y)));            \
                xv.z = clip01(fmaf(s, (ba).z, fmaf(os, (wa).z, (fb).z)));            \
                xv.w = clip01(fmaf(s, (ba).w, fmaf(os, (wa).w, (fb).w)));            \
            }                                                                        \
            const int d = (hf) * 256 + 4 * (i);                                      \
            *reinterpret_cast<float4*>(&lds[e * XPITCH + (d >> 6) * 68 + (d & 63)]) = xv; \
        }
        MIXW(wa0, ba0, fb0, r,      0)
        MIXW(wa1, ba1, fb1, r + 32, 0)
        MIXW(wa0, ba0, fb0, r,      1)
        MIXW(wa1, ba1, fb1, r + 32, 1)
        #undef MIXW
    }
    __syncthreads();

    // ---- Phase C: layer 1 (512 -> 32) for all 8 elements; W1 read once per block ----
    {
        const int j = t >> 3;
        const int c = t & 7;
        const float* w1p = W1 + j * 512 + c * 64;
        float acc[NB] = {0.f, 0.f, 0.f, 0.f, 0.f, 0.f, 0.f, 0.f};
        #pragma unroll
        for (int blk = 0; blk < 4; ++blk) {
            const float4 wv0 = reinterpret_cast<const float4*>(w1p + blk * 16)[0];
            const float4 wv1 = reinterpret_cast<const float4*>(w1p + blk * 16)[1];
            const float4 wv2 = reinterpret_cast<const float4*>(w1p + blk * 16)[2];
            const float4 wv3 = reinterpret_cast<const float4*>(w1p + blk * 16)[3];
            #pragma unroll
            for (int e = 0; e < NB; ++e) {
                const float* xp = &lds[e * XPITCH + c * 68 + blk * 16];
                const float4 x0 = *reinterpret_cast<const float4*>(xp + 0);
                const float4 x1 = *reinterpret_cast<const float4*>(xp + 4);
                const float4 x2 = *reinterpret_cast<const float4*>(xp + 8);
                const float4 x3 = *reinterpret_cast<const float4*>(xp + 12);
                float a = acc[e];
                a = fmaf(wv0.x, x0.x, a); a = fmaf(wv0.y, x0.y, a);
                a = fmaf(wv0.z, x0.z, a); a = fmaf(wv0.w, x0.w, a);
                a = fmaf(wv1.x, x1.x, a); a = fmaf(wv1.y, x1.y, a);
                a = fmaf(wv1.z, x1.z, a); a = fmaf(wv1.w, x1.w, a);
                a = fmaf(wv2.x, x2.x, a); a = fmaf(wv2.y, x2.y, a);
                a = fmaf(wv2.z, x2.z, a); a = fmaf(wv2.w, x2.w, a);
                a = fmaf(wv3.x, x3.x, a); a = fmaf(wv3.y, x3.y, a);
                a = fmaf(wv3.z, x3.z, a); a = fmaf(wv3.w, x3.w, a);
                acc[e] = a;
            }
        }
        #pragma unroll
        for (int e = 0; e < NB; ++e) {
            acc[e] += __shfl_xor(acc[e], 1);
            acc[e] += __shfl_xor(acc[e], 2);
            acc[e] += __shfl_xor(acc[e], 4);
        }
        if (c == 0) {
            const float bj = b1[j];
            #pragma unroll
            for (int e = 0; e < NB; ++e)
                y1s[e][j] = clip01(acc[e] + bj);
        }
    }
    __syncthreads();

    // ---- Phase D: layer 2 (32 -> 32) + output head ----
    {
        const int e = t >> 5, i = t & 31;
        const float4* w2p = reinterpret_cast<const float4*>(W2 + i * 32);
        float a2 = b2[i];
        #pragma unroll
        for (int kq = 0; kq < 8; ++kq) {
            const float4 wq = w2p[kq];
            const float4 yq = *reinterpret_cast<const float4*>(&y1s[e][kq * 4]);
            a2 = fmaf(wq.x, yq.x, a2); a2 = fmaf(wq.y, yq.y, a2);
            a2 = fmaf(wq.z, yq.z, a2); a2 = fmaf(wq.w, yq.w, a2);
        }
        a2 = clip01(a2);
        float p = a2 * Wo[i];
        p += __shfl_xor(p, 1);  p += __shfl_xor(p, 2);
        p += __shfl_xor(p, 4);  p += __shfl_xor(p, 8);
        p += __shfl_xor(p, 16);
        if (i == 0) out[b0 + e] = p + bo[0];
    }
}

// ---------------- fallback 1: R8 fused int8 kernel (if ws fits qt only) ----------------
__global__ __launch_bounds__(256, 8) void nnue_i8_fused(
    const int* __restrict__ wf, const int* __restrict__ bf,
    const float* __restrict__ stm, const uint* __restrict__ qt,
    const float* __restrict__ scales,
    const float* __restrict__ ft_bias,
    const float* __restrict__ W1, const float* __restrict__ b1,
    const float* __restrict__ W2, const float* __restrict__ b2,
    const float* __restrict__ Wo, const float* __restrict__ bo,
    float* __restrict__ out)
{
    __shared__ float lds[NB * XPITCH];
    __shared__ float y1s[NB][32];

    const int t   = threadIdx.x;
    const int l   = t & 63;
    const int w   = t >> 6;
    const int sub = l & 31;
    const int b0  = blockIdx.x * NB;

    {
        const int side = w & 1;
        const int eb   = w >> 1;
        const int* fp  = side ? bf : wf;
        #pragma unroll
        for (int g = 0; g < 4; ++g) {
            const int bag = g * 4 + w;
            const int iv  = fp[(size_t)(b0 + 2 * g + eb) * KFEAT + sub];
            float a0 = 0.f, a1 = 0.f, a2 = 0.f, a3 = 0.f;
            #pragma unroll
            for (int k = 0; k < KFEAT; ++k) {
                const int row  = __builtin_amdgcn_readlane(iv, k);
                const int  q   = (int)qt[(size_t)row * 64 + l];
                const float sc = scales[row];
                a0 = fmaf((float)((q << 24) >> 24), sc, a0);
                a1 = fmaf((float)((q << 16) >> 24), sc, a1);
                a2 = fmaf((float)((q <<  8) >> 24), sc, a2);
                a3 = fmaf((float)( q        >> 24), sc, a3);
            }
            *reinterpret_cast<float4*>(&lds[bag * APITCH + l * 4]) =
                make_float4(a0, a1, a2, a3);
        }
    }
    __syncthreads();

    {
        const int e = t >> 5, r = t & 31;
        const float s  = stm[b0 + e];
        const float os = 1.0f - s;
        const float4 wa0 = *reinterpret_cast<const float4*>(&lds[(2 * e + 0) * APITCH + 4 * r]);
        const float4 ba0 = *reinterpret_cast<const float4*>(&lds[(2 * e + 1) * APITCH + 4 * r]);
        const float4 wa1 = *reinterpret_cast<const float4*>(&lds[(2 * e + 0) * APITCH + 4 * (r + 32)]);
        const float4 ba1 = *reinterpret_cast<const float4*>(&lds[(2 * e + 1) * APITCH + 4 * (r + 32)]);
        const float4 fb0 = reinterpret_cast<const float4*>(ft_bias)[r];
        const float4 fb1 = reinterpret_cast<const float4*>(ft_bias)[r + 32];
        __syncthreads();

        #define MIXW(wa, ba, fb, i, hf)                                              \
        {                                                                            \
            float4 xv;                                                               \
            if (hf == 0) {                                                           \
                xv.x = clip01(fmaf(s, (wa).x, fmaf(os, (ba).x, (fb).x)));            \
                xv.y = clip01(fmaf(s, (wa).y, fmaf(os, (ba).y, (fb).y)));            \
                xv.z = clip01(fmaf(s, (wa).z, fmaf(os, (ba).z, (fb).z)));            \
                xv.w = clip01(fmaf(s, (wa).w, fmaf(os, (ba).w, (fb).w)));            \
            } else {                                                                 \
                xv.x = clip01(fmaf(s, (ba).x, fmaf(os, (wa).x, (fb).x)));            \
                xv.y = clip01(fmaf(s, (ba).y, fmaf(os, (wa).y, (fb).y)));            \
                xv.z = clip01(fmaf(s, (ba).z, fmaf(os, (wa).z, (fb).z)));            \
                xv.w = clip01(fmaf(s, (ba).w, fmaf(os, (wa).w, (fb).w)));            \
            }                                                                        \
            const int d = (hf) * 256 + 4 * (i);                                      \
            *reinterpret_cast<float4*>(&lds[e * XPITCH + (d >> 6) * 68 + (d & 63)]) = xv; \
        }
        MIXW(wa0, ba0, fb0, r,      0)
        MIXW(wa1, ba1, fb1, r + 32, 0)
        MIXW(wa0, ba0, fb0, r,      1)
        MIXW(wa1, ba1, fb1, r + 32, 1)
        #undef MIXW
    }
    __syncthreads();

    {
        const int j = t >> 3;
        const int c = t & 7;
        const float* w1p = W1 + j * 512 + c * 64;
        float acc[NB] = {0.f, 0.f, 0.f, 0.f, 0.f, 0.f, 0.f, 0.f};
        #pragma unroll
        for (int blk = 0; blk < 4; ++blk) {
            const float4 wv0 = reinterpret_cast<const float4*>(w1p + blk * 16)[0];
            const float4 wv1 = reinterpret_cast<const float4*>(w1p + blk * 16)[1];
            const float4 wv2 = reinterpret_cast<const float4*>(w1p + blk * 16)[2];
            const float4 wv3 = reinterpret_cast<const float4*>(w1p + blk * 16)[3];
            #pragma unroll
            for (int e = 0; e < NB; ++e) {
                const float* xp = &lds[e * XPITCH + c * 68 + blk * 16];
                const float4 x0 = *reinterpret_cast<const float4*>(xp + 0);
                const float4 x1 = *reinterpret_cast<const float4*>(xp + 4);
                const float4 x2 = *reinterpret_cast<const float4*>(xp + 8);
                const float4 x3 = *reinterpret_cast<const float4*>(xp + 12);
                float a = acc[e];
                a = fmaf(wv0.x, x0.x, a); a = fmaf(wv0.y, x0.y, a);
                a = fmaf(wv0.z, x0.z, a); a = fmaf(wv0.w, x0.w, a);
                a = fmaf(wv1.x, x1.x, a); a = fmaf(wv1.y, x1.y, a);
                a = fmaf(wv1.z, x1.z, a); a = fmaf(wv1.w, x1.w, a);
                a = fmaf(wv2.x, x2.x, a); a = fmaf(wv2.y, x2.y, a);
                a = fmaf(wv2.z, x2.z, a); a = fmaf(wv2.w, x2.w, a);
                a = fmaf(wv3.x, x3.x, a); a = fmaf(wv3.y, x3.y, a);
                a = fmaf(wv3.z, x3.z, a); a = fmaf(wv3.w, x3.w, a);
                acc[e] = a;
            }
        }
        #pragma unroll
        for (int e = 0; e < NB; ++e) {
            acc[e] += __shfl_xor(acc[e], 1);
            acc[e] += __shfl_xor(acc[e], 2);
            acc[e] += __shfl_xor(acc[e], 4);
        }
        if (c == 0) {
            const float bj = b1[j];
            #pragma unroll
            for (int e = 0; e < NB; ++e)
                y1s[e][j] = clip01(acc[e] + bj);
        }
    }
    __syncthreads();

    {
        const int e = t >> 5, i = t & 31;
        const float4* w2p = reinterpret_cast<const float4*>(W2 + i * 32);
        float a2 = b2[i];
        #pragma unroll
        for (int kq = 0; kq < 8; ++kq) {
            const float4 wq = w2p[kq];
            const float4 yq = *reinterpret_cast<const float4*>(&y1s[e][kq * 4]);
            a2 = fmaf(wq.x, yq.x, a2); a2 = fmaf(wq.y, yq.y, a2);
            a2 = fmaf(wq.z, yq.z, a2); a2 = fmaf(wq.w, yq.w, a2);
        }
        a2 = clip01(a2);
        float p = a2 * Wo[i];
        p += __shfl_xor(p, 1);  p += __shfl_xor(p, 2);
        p += __shfl_xor(p, 4);  p += __shfl_xor(p, 8);
        p += __shfl_xor(p, 16);
        if (i == 0) out[b0 + e] = p + bo[0];
    }
}

// ---------------- fallback 2: fp32 table path (if ws too small for anything) ----------------
__global__ __launch_bounds__(256, 6) void nnue_fused_kernel(
    const int* __restrict__ wf, const int* __restrict__ bf,
    const float* __restrict__ stm, const float* __restrict__ table,
    const float* __restrict__ ft_bias,
    const float* __restrict__ W1, const float* __restrict__ b1,
    const float* __restrict__ W2, const float* __restrict__ b2,
    const float* __restrict__ Wo, const float* __restrict__ bo,
    float* __restrict__ out)
{
    __shared__ float4 accs[4][64];
    __shared__ float  xs[2 * 4 * 132];
    __shared__ float  y1s[2][32];

    const int t    = threadIdx.x;
    const int l    = t & 63;
    const int w    = t >> 6;
    const int side = w & 1;
    const int esub = w >> 1;

    const float4 ftb4 = reinterpret_cast<const float4*>(ft_bias)[l];
    const int*   fptr = side ? bf : wf;

    const int j = t >> 3;
    const int c = t & 7;
    const float* w1p = W1 + j * 512 + c * 64;
    const float* x0p = &xs[(0 * 4 + (c >> 1)) * 132 + (c & 1) * 64];
    const float* x1p = &xs[(1 * 4 + (c >> 1)) * 132 + (c & 1) * 64];

    for (int it = 0; it < 8 / 2; ++it) {
        const int b0 = blockIdx.x * 8 + it * 2;

        int idxv = fptr[(size_t)(b0 + esub) * KFEAT + (l & 31)];
        float4 acc = ftb4;
        #pragma unroll
        for (int k = 0; k < KFEAT; ++k) {
            const int row = __builtin_amdgcn_readlane(idxv, k);
            const float4 v = reinterpret_cast<const float4*>(table)[(size_t)row * 64 + l];
            acc.x += v.x; acc.y += v.y; acc.z += v.z; acc.w += v.w;
        }
        accs[w][l] = acc;
        __syncthreads();

        {
            const int e  = t >> 7;
            const int hf = (t >> 6) & 1;
            const int i  = t & 63;
            const float s  = stm[b0 + e];
            const float os = 1.0f - s;
            const float4 wa = accs[e * 2 + 0][i];
            const float4 ba = accs[e * 2 + 1][i];
            float4 x;
            if (hf == 0) {
                x.x = clip01(s * wa.x + os * ba.x);
                x.y = clip01(s * wa.y + os * ba.y);
                x.z = clip01(s * wa.z + os * ba.z);
                x.w = clip01(s * wa.w + os * ba.w);
            } else {
                x.x = clip01(s * ba.x + os * wa.x);
                x.y = clip01(s * ba.y + os * wa.y);
                x.z = clip01(s * ba.z + os * wa.z);
                x.w = clip01(s * ba.w + os * wa.w);
            }
            const int slot = hf * 64 + i;
            const int g = slot >> 5, i4 = slot & 31;
            *reinterpret_cast<float4*>(&xs[(e * 4 + g) * 132 + i4 * 4]) = x;
        }
        __syncthreads();

        float a0 = 0.0f, a1 = 0.0f;
        #pragma unroll 16
        for (int ii = 0; ii < 64; ++ii) {
            const float wv = w1p[ii];
            a0 = fmaf(wv, x0p[ii], a0);
            a1 = fmaf(wv, x1p[ii], a1);
        }
        a0 += __shfl_xor(a0, 1); a0 += __shfl_xor(a0, 2); a0 += __shfl_xor(a0, 4);
        a1 += __shfl_xor(a1, 1); a1 += __shfl_xor(a1, 2); a1 += __shfl_xor(a1, 4);
        if (c == 0) {
            const float bj = b1[j];
            y1s[0][j] = clip01(a0 + bj);
            y1s[1][j] = clip01(a1 + bj);
        }
        __syncthreads();

        if (t < 64) {
            const int e = t >> 5, i = t & 31;
            float a2 = b2[i];
            #pragma unroll
            for (int k2 = 0; k2 < 32; ++k2)
                a2 = fmaf(y1s[e][k2], W2[i * 32 + k2], a2);
            a2 = clip01(a2);
            float p = a2 * Wo[i];
            p += __shfl_xor(p, 1);  p += __shfl_xor(p, 2);
            p += __shfl_xor(p, 4);  p += __shfl_xor(p, 8);
            p += __shfl_xor(p, 16);
            if (i == 0) out[b0 + e] = p + bo[0];
        }
        __syncthreads();
    }
}

extern "C" void kernel_launch(void* const* d_in, const int* in_sizes, int n_in,
                              void* d_out, int out_size, void* d_ws, size_t ws_size,
                              hipStream_t stream) {
    const int*   wf      = (const int*)  d_in[0];
    const int*   bf      = (const int*)  d_in[2];
    const float* stm     = (const float*)d_in[4];
    const float* table   = (const float*)d_in[5];
    const float* ft_bias = (const float*)d_in[6];
    const float* W1      = (const float*)d_in[7];
    const float* b1      = (const float*)d_in[8];
    const float* W2      = (const float*)d_in[9];
    const float* b2      = (const float*)d_in[10];
    const float* Wo      = (const float*)d_in[11];
    const float* bo      = (const float*)d_in[12];
    float*       out     = (float*)d_out;

    const int B = in_sizes[1];                   // 16384
    const int tbl_elems = in_sizes[5];           // 40960*256
    const int nrows = tbl_elems / 256;           // 40960
    const size_t qbytes  = (size_t)tbl_elems;    // int8 table bytes
    const size_t sbytes  = (size_t)nrows * sizeof(float);
    const size_t abytes  = (size_t)B * 2 * 256 * sizeof(float);   // bag sums, 33.5 MB
    const size_t need_q  = qbytes + sbytes;
    const size_t need_sp = need_q + abytes;

    if (ws_size >= need_sp) {
        uint*  qt     = (uint*)d_ws;
        float* scales = (float*)((char*)d_ws + qbytes);
        float* accs   = (float*)((char*)d_ws + need_q);
        quantize_table_i8<<<(nrows + 3) / 4, 256, 0, stream>>>(table, qt, scales, nrows);
        gather_i8_kernel<<<(B * 2) / 4, 256, 0, stream>>>(wf, bf, qt, scales, accs);
        mlp_kernel<<<B / NB, 256, 0, stream>>>(
            accs, stm, ft_bias, W1, b1, W2, b2, Wo, bo, out);
    } else if (ws_size >= need_q) {
        uint*  qt     = (uint*)d_ws;
        float* scales = (float*)((char*)d_ws + qbytes);
        quantize_table_i8<<<(nrows + 3) / 4, 256, 0, stream>>>(table, qt, scales, nrows);
        nnue_i8_fused<<<B / NB, 256, 0, stream>>>(
            wf, bf, stm, qt, scales, ft_bias, W1, b1, W2, b2, Wo, bo, out);
    } else {
        nnue_fused_kernel<<<B / 8, 256, 0, stream>>>(
            wf, bf, stm, table, ft_bias, W1, b1, W2, b2, Wo, bo, out);
    }
}

// Round 14
// 65.367 us; speedup vs baseline: 1.2008x; 1.2008x over previous
//
#include <hip/hip_runtime.h>

#define KFEAT 32
#define NB 8            // batch elements per block
#define XPITCH 544      // floats per element row in xs (8 chunks * 68)
#define APITCH 272      // floats per bag row in accs overlay (= XPITCH/2)

__device__ __forceinline__ float clip01(float v) {
    return fminf(fmaxf(v, 0.0f), 1.0f);
}

// ---- one-pass per-row absmax + int8 quantize (one wave per row) ----
__global__ __launch_bounds__(256) void quantize_table_i8(
    const float* __restrict__ src, uint* __restrict__ qt,
    float* __restrict__ scales, int nrows)
{
    const int row = blockIdx.x * 4 + (threadIdx.x >> 6);
    const int l   = threadIdx.x & 63;
    if (row >= nrows) return;

    const float4 v = reinterpret_cast<const float4*>(src)[(size_t)row * 64 + l];
    float m = fmaxf(fmaxf(fabsf(v.x), fabsf(v.y)), fmaxf(fabsf(v.z), fabsf(v.w)));
    m = fmaxf(m, __shfl_xor(m, 1));
    m = fmaxf(m, __shfl_xor(m, 2));
    m = fmaxf(m, __shfl_xor(m, 4));
    m = fmaxf(m, __shfl_xor(m, 8));
    m = fmaxf(m, __shfl_xor(m, 16));
    m = fmaxf(m, __shfl_xor(m, 32));

    const float inv = (m > 0.0f) ? 127.0f / m : 0.0f;
    const int b0 = ((int)rintf(v.x * inv)) & 0xFF;
    const int b1 = ((int)rintf(v.y * inv)) & 0xFF;
    const int b2 = ((int)rintf(v.z * inv)) & 0xFF;
    const int b3 = ((int)rintf(v.w * inv)) & 0xFF;
    qt[(size_t)row * 64 + l] = (uint)b0 | ((uint)b1 << 8) | ((uint)b2 << 16) | ((uint)b3 << 24);
    if (l == 0) scales[row] = m * (1.0f / 127.0f);
}

// ---------------- main fused kernel: int8 table, ASYNC global_load_lds gather ----------------
// Phase A stages rows via global_load_lds (no VGPR destinations -> HW queue depth,
// not the register allocator, sets loads-in-flight). 2-deep octet pipeline with
// counted vmcnt waits (T3/T4) and sched_barrier fences (rule #18).
__global__ __launch_bounds__(256, 4) void nnue_i8_async(
    const int* __restrict__ wf, const int* __restrict__ bf,
    const float* __restrict__ stm, const uint* __restrict__ qt,
    const float* __restrict__ scales,
    const float* __restrict__ ft_bias,
    const float* __restrict__ W1, const float* __restrict__ b1,
    const float* __restrict__ W2, const float* __restrict__ b2,
    const float* __restrict__ Wo, const float* __restrict__ bo,
    float* __restrict__ out)
{
    // Union region: first accs[16][APITCH] (raw bag sums), then xs[8][XPITCH].
    __shared__ float lds[NB * XPITCH];
    __shared__ float y1s[NB][32];
    __shared__ uint  stage[4][2][8 * 64];   // per-wave double buffer: 8 rows x 256B

    const int t   = threadIdx.x;
    const int l   = t & 63;
    const int w   = t >> 6;     // wave 0..3
    const int sub = l & 31;
    const int b0  = blockIdx.x * NB;

    // ---- Phase A: 4 bags per wave, async-staged octet pipeline ----
    {
        const int side = w & 1;
        const int eb   = w >> 1;
        const int* fp  = side ? bf : wf;

        int ivs[4];
        #pragma unroll
        for (int g = 0; g < 4; ++g)
            ivs[g] = fp[(size_t)(b0 + 2 * g + eb) * KFEAT + sub];

        float a0 = 0.f, a1 = 0.f, a2 = 0.f, a3 = 0.f;

        #define GLD1(iv, kk, sb, j)                                                  \
        {                                                                            \
            const int row_ = __builtin_amdgcn_readlane((iv), (kk));                  \
            __builtin_amdgcn_global_load_lds(                                        \
                (const __attribute__((address_space(1))) void*)(qt + (size_t)row_ * 64 + l), \
                (__attribute__((address_space(3))) void*)((sb) + (j) * 64),          \
                4, 0, 0);                                                            \
        }
        #define ISSUE_OCT(o)                                                         \
        {                                                                            \
            const int iv_ = ivs[(o) >> 2];                                           \
            uint* sb_ = &stage[w][(o) & 1][0];                                       \
            GLD1(iv_, ((o) & 3) * 8 + 0, sb_, 0)                                     \
            GLD1(iv_, ((o) & 3) * 8 + 1, sb_, 1)                                     \
            GLD1(iv_, ((o) & 3) * 8 + 2, sb_, 2)                                     \
            GLD1(iv_, ((o) & 3) * 8 + 3, sb_, 3)                                     \
            GLD1(iv_, ((o) & 3) * 8 + 4, sb_, 4)                                     \
            GLD1(iv_, ((o) & 3) * 8 + 5, sb_, 5)                                     \
            GLD1(iv_, ((o) & 3) * 8 + 6, sb_, 6)                                     \
            GLD1(iv_, ((o) & 3) * 8 + 7, sb_, 7)                                     \
        }
        #define CONS1(iv, kk, sb, j)                                                 \
        {                                                                            \
            const int row_  = __builtin_amdgcn_readlane((iv), (kk));                 \
            const float sc_ = scales[row_];                                          \
            const int q_    = (int)(sb)[(j) * 64 + l];                               \
            a0 = fmaf((float)((q_ << 24) >> 24), sc_, a0);                           \
            a1 = fmaf((float)((q_ << 16) >> 24), sc_, a1);                           \
            a2 = fmaf((float)((q_ <<  8) >> 24), sc_, a2);                           \
            a3 = fmaf((float)( q_        >> 24), sc_, a3);                           \
        }
        #define CONS_OCT(o)                                                          \
        {                                                                            \
            const int iv_ = ivs[(o) >> 2];                                           \
            const uint* sb_ = &stage[w][(o) & 1][0];                                 \
            CONS1(iv_, ((o) & 3) * 8 + 0, sb_, 0)                                    \
            CONS1(iv_, ((o) & 3) * 8 + 1, sb_, 1)                                    \
            CONS1(iv_, ((o) & 3) * 8 + 2, sb_, 2)                                    \
            CONS1(iv_, ((o) & 3) * 8 + 3, sb_, 3)                                    \
            CONS1(iv_, ((o) & 3) * 8 + 4, sb_, 4)                                    \
            CONS1(iv_, ((o) & 3) * 8 + 5, sb_, 5)                                    \
            CONS1(iv_, ((o) & 3) * 8 + 6, sb_, 6)                                    \
            CONS1(iv_, ((o) & 3) * 8 + 7, sb_, 7)                                    \
        }
        #define WAITVM8 { asm volatile("s_waitcnt vmcnt(8)" ::: "memory"); __builtin_amdgcn_sched_barrier(0); }
        #define WAITVM0 { asm volatile("s_waitcnt vmcnt(0)" ::: "memory"); __builtin_amdgcn_sched_barrier(0); }
        #define FLGKM   { asm volatile("s_waitcnt lgkmcnt(0)" ::: "memory"); __builtin_amdgcn_sched_barrier(0); }
        #define STORE_BAG(g)                                                         \
            *reinterpret_cast<float4*>(&lds[((g) * 4 + w) * APITCH + l * 4]) =       \
                make_float4(a0, a1, a2, a3);

        ISSUE_OCT(0)
        ISSUE_OCT(1)
        // bag 0 (octets 0-3)
        WAITVM8  CONS_OCT(0)   FLGKM  ISSUE_OCT(2)
        WAITVM8  CONS_OCT(1)   FLGKM  ISSUE_OCT(3)
        WAITVM8  CONS_OCT(2)   FLGKM  ISSUE_OCT(4)
        WAITVM8  CONS_OCT(3)   FLGKM  ISSUE_OCT(5)
        STORE_BAG(0)  a0 = a1 = a2 = a3 = 0.f;
        // bag 1 (octets 4-7)
        WAITVM8  CONS_OCT(4)   FLGKM  ISSUE_OCT(6)
        WAITVM8  CONS_OCT(5)   FLGKM  ISSUE_OCT(7)
        WAITVM8  CONS_OCT(6)   FLGKM  ISSUE_OCT(8)
        WAITVM8  CONS_OCT(7)   FLGKM  ISSUE_OCT(9)
        STORE_BAG(1)  a0 = a1 = a2 = a3 = 0.f;
        // bag 2 (octets 8-11)
        WAITVM8  CONS_OCT(8)   FLGKM  ISSUE_OCT(10)
        WAITVM8  CONS_OCT(9)   FLGKM  ISSUE_OCT(11)
        WAITVM8  CONS_OCT(10)  FLGKM  ISSUE_OCT(12)
        WAITVM8  CONS_OCT(11)  FLGKM  ISSUE_OCT(13)
        STORE_BAG(2)  a0 = a1 = a2 = a3 = 0.f;
        // bag 3 (octets 12-15)
        WAITVM8  CONS_OCT(12)  FLGKM  ISSUE_OCT(14)
        WAITVM8  CONS_OCT(13)  FLGKM  ISSUE_OCT(15)
        WAITVM8  CONS_OCT(14)
        WAITVM0  CONS_OCT(15)
        STORE_BAG(3)

        #undef GLD1
        #undef ISSUE_OCT
        #undef CONS1
        #undef CONS_OCT
        #undef WAITVM8
        #undef WAITVM0
        #undef FLGKM
        #undef STORE_BAG
    }
    __syncthreads();

    // ---- Phase B: mix + clip, in-place overlay (read all -> barrier -> write) ----
    {
        const int e = t >> 5, r = t & 31;
        const float s  = stm[b0 + e];
        const float os = 1.0f - s;
        const float4 wa0 = *reinterpret_cast<const float4*>(&lds[(2 * e + 0) * APITCH + 4 * r]);
        const float4 ba0 = *reinterpret_cast<const float4*>(&lds[(2 * e + 1) * APITCH + 4 * r]);
        const float4 wa1 = *reinterpret_cast<const float4*>(&lds[(2 * e + 0) * APITCH + 4 * (r + 32)]);
        const float4 ba1 = *reinterpret_cast<const float4*>(&lds[(2 * e + 1) * APITCH + 4 * (r + 32)]);
        const float4 fb0 = reinterpret_cast<const float4*>(ft_bias)[r];
        const float4 fb1 = reinterpret_cast<const float4*>(ft_bias)[r + 32];
        __syncthreads();

        // d = hf*256 + 4*i  ->  xs addr: e*XPITCH + (d>>6)*68 + (d&63)
        #define MIXW(wa, ba, fb, i, hf)                                              \
        {                                                                            \
            float4 xv;                                                               \
            if (hf == 0) {                                                           \
                xv.x = clip01(fmaf(s, (wa).x, fmaf(os, (ba).x, (fb).x)));            \
                xv.y = clip01(fmaf(s, (wa).y, fmaf(os, (ba).y, (fb).y)));            \
                xv.z = clip01(fmaf(s, (wa).z, fmaf(os, (ba).z, (fb).z)));            \
                xv.w = clip01(fmaf(s, (wa).w, fmaf(os, (ba).w, (fb).w)));            \
            } else {                                                                 \
                xv.x = clip01(fmaf(s, (ba).x, fmaf(os, (wa).x, (fb).x)));            \
                xv.y = clip01(fmaf(s, (ba).y, fmaf(os, (wa).y, (fb).y)));            \
                xv.z = clip01(fmaf(s, (ba).z, fmaf(os, (wa).z, (fb).z)));            \
                xv.w = clip01(fmaf(s, (ba).w, fmaf(os, (wa).w, (fb).w)));            \
            }                                                                        \
            const int d = (hf) * 256 + 4 * (i);                                      \
            *reinterpret_cast<float4*>(&lds[e * XPITCH + (d >> 6) * 68 + (d & 63)]) = xv; \
        }
        MIXW(wa0, ba0, fb0, r,      0)
        MIXW(wa1, ba1, fb1, r + 32, 0)
        MIXW(wa0, ba0, fb0, r,      1)
        MIXW(wa1, ba1, fb1, r + 32, 1)
        #undef MIXW
    }
    __syncthreads();

    // ---- Phase C: layer 1 (512 -> 32) for all 8 elements; W1 read once per block ----
    {
        const int j = t >> 3;   // output neuron 0..31
        const int c = t & 7;    // 64-dim chunk 0..7
        const float* w1p = W1 + j * 512 + c * 64;
        float acc[NB] = {0.f, 0.f, 0.f, 0.f, 0.f, 0.f, 0.f, 0.f};
        #pragma unroll
        for (int blk = 0; blk < 4; ++blk) {
            const float4 wv0 = reinterpret_cast<const float4*>(w1p + blk * 16)[0];
            const float4 wv1 = reinterpret_cast<const float4*>(w1p + blk * 16)[1];
            const float4 wv2 = reinterpret_cast<const float4*>(w1p + blk * 16)[2];
            const float4 wv3 = reinterpret_cast<const float4*>(w1p + blk * 16)[3];
            #pragma unroll
            for (int e = 0; e < NB; ++e) {
                const float* xp = &lds[e * XPITCH + c * 68 + blk * 16];
                const float4 x0 = *reinterpret_cast<const float4*>(xp + 0);
                const float4 x1 = *reinterpret_cast<const float4*>(xp + 4);
                const float4 x2 = *reinterpret_cast<const float4*>(xp + 8);
                const float4 x3 = *reinterpret_cast<const float4*>(xp + 12);
                float a = acc[e];
                a = fmaf(wv0.x, x0.x, a); a = fmaf(wv0.y, x0.y, a);
                a = fmaf(wv0.z, x0.z, a); a = fmaf(wv0.w, x0.w, a);
                a = fmaf(wv1.x, x1.x, a); a = fmaf(wv1.y, x1.y, a);
                a = fmaf(wv1.z, x1.z, a); a = fmaf(wv1.w, x1.w, a);
                a = fmaf(wv2.x, x2.x, a); a = fmaf(wv2.y, x2.y, a);
                a = fmaf(wv2.z, x2.z, a); a = fmaf(wv2.w, x2.w, a);
                a = fmaf(wv3.x, x3.x, a); a = fmaf(wv3.y, x3.y, a);
                a = fmaf(wv3.z, x3.z, a); a = fmaf(wv3.w, x3.w, a);
                acc[e] = a;
            }
        }
        #pragma unroll
        for (int e = 0; e < NB; ++e) {
            acc[e] += __shfl_xor(acc[e], 1);
            acc[e] += __shfl_xor(acc[e], 2);
            acc[e] += __shfl_xor(acc[e], 4);
        }
        if (c == 0) {
            const float bj = b1[j];
            #pragma unroll
            for (int e = 0; e < NB; ++e)
                y1s[e][j] = clip01(acc[e] + bj);
        }
    }
    __syncthreads();

    // ---- Phase D: layer 2 (32 -> 32) + output head; thread = (element, neuron) ----
    {
        const int e = t >> 5, i = t & 31;
        const float4* w2p = reinterpret_cast<const float4*>(W2 + i * 32);
        float a2 = b2[i];
        #pragma unroll
        for (int kq = 0; kq < 8; ++kq) {
            const float4 wq = w2p[kq];
            const float4 yq = *reinterpret_cast<const float4*>(&y1s[e][kq * 4]);
            a2 = fmaf(wq.x, yq.x, a2); a2 = fmaf(wq.y, yq.y, a2);
            a2 = fmaf(wq.z, yq.z, a2); a2 = fmaf(wq.w, yq.w, a2);
        }
        a2 = clip01(a2);
        float p = a2 * Wo[i];
        p += __shfl_xor(p, 1);  p += __shfl_xor(p, 2);
        p += __shfl_xor(p, 4);  p += __shfl_xor(p, 8);
        p += __shfl_xor(p, 16);
        if (i == 0) out[b0 + e] = p + bo[0];
    }
}

// ---------------- fallback: fp32 table path (if ws too small) ----------------
__global__ __launch_bounds__(256, 6) void nnue_fused_kernel(
    const int* __restrict__ wf, const int* __restrict__ bf,
    const float* __restrict__ stm, const float* __restrict__ table,
    const float* __restrict__ ft_bias,
    const float* __restrict__ W1, const float* __restrict__ b1,
    const float* __restrict__ W2, const float* __restrict__ b2,
    const float* __restrict__ Wo, const float* __restrict__ bo,
    float* __restrict__ out)
{
    __shared__ float4 accs[4][64];
    __shared__ float  xs[2 * 4 * 132];
    __shared__ float  y1s[2][32];

    const int t    = threadIdx.x;
    const int l    = t & 63;
    const int w    = t >> 6;
    const int side = w & 1;
    const int esub = w >> 1;

    const float4 ftb4 = reinterpret_cast<const float4*>(ft_bias)[l];
    const int*   fptr = side ? bf : wf;

    const int j = t >> 3;
    const int c = t & 7;
    const float* w1p = W1 + j * 512 + c * 64;
    const float* x0p = &xs[(0 * 4 + (c >> 1)) * 132 + (c & 1) * 64];
    const float* x1p = &xs[(1 * 4 + (c >> 1)) * 132 + (c & 1) * 64];

    for (int it = 0; it < 8 / 2; ++it) {
        const int b0 = blockIdx.x * 8 + it * 2;

        int idxv = fptr[(size_t)(b0 + esub) * KFEAT + (l & 31)];
        float4 acc = ftb4;
        #pragma unroll
        for (int k = 0; k < KFEAT; ++k) {
            const int row = __builtin_amdgcn_readlane(idxv, k);
            const float4 v = reinterpret_cast<const float4*>(table)[(size_t)row * 64 + l];
            acc.x += v.x; acc.y += v.y; acc.z += v.z; acc.w += v.w;
        }
        accs[w][l] = acc;
        __syncthreads();

        {
            const int e  = t >> 7;
            const int hf = (t >> 6) & 1;
            const int i  = t & 63;
            const float s  = stm[b0 + e];
            const float os = 1.0f - s;
            const float4 wa = accs[e * 2 + 0][i];
            const float4 ba = accs[e * 2 + 1][i];
            float4 x;
            if (hf == 0) {
                x.x = clip01(s * wa.x + os * ba.x);
                x.y = clip01(s * wa.y + os * ba.y);
                x.z = clip01(s * wa.z + os * ba.z);
                x.w = clip01(s * wa.w + os * ba.w);
            } else {
                x.x = clip01(s * ba.x + os * wa.x);
                x.y = clip01(s * ba.y + os * wa.y);
                x.z = clip01(s * ba.z + os * wa.z);
                x.w = clip01(s * ba.w + os * wa.w);
            }
            const int slot = hf * 64 + i;
            const int g = slot >> 5, i4 = slot & 31;
            *reinterpret_cast<float4*>(&xs[(e * 4 + g) * 132 + i4 * 4]) = x;
        }
        __syncthreads();

        float a0 = 0.0f, a1 = 0.0f;
        #pragma unroll 16
        for (int ii = 0; ii < 64; ++ii) {
            const float wv = w1p[ii];
            a0 = fmaf(wv, x0p[ii], a0);
            a1 = fmaf(wv, x1p[ii], a1);
        }
        a0 += __shfl_xor(a0, 1); a0 += __shfl_xor(a0, 2); a0 += __shfl_xor(a0, 4);
        a1 += __shfl_xor(a1, 1); a1 += __shfl_xor(a1, 2); a1 += __shfl_xor(a1, 4);
        if (c == 0) {
            const float bj = b1[j];
            y1s[0][j] = clip01(a0 + bj);
            y1s[1][j] = clip01(a1 + bj);
        }
        __syncthreads();

        if (t < 64) {
            const int e = t >> 5, i = t & 31;
            float a2 = b2[i];
            #pragma unroll
            for (int k2 = 0; k2 < 32; ++k2)
                a2 = fmaf(y1s[e][k2], W2[i * 32 + k2], a2);
            a2 = clip01(a2);
            float p = a2 * Wo[i];
            p += __shfl_xor(p, 1);  p += __shfl_xor(p, 2);
            p += __shfl_xor(p, 4);  p += __shfl_xor(p, 8);
            p += __shfl_xor(p, 16);
            if (i == 0) out[b0 + e] = p + bo[0];
        }
        __syncthreads();
    }
}

extern "C" void kernel_launch(void* const* d_in, const int* in_sizes, int n_in,
                              void* d_out, int out_size, void* d_ws, size_t ws_size,
                              hipStream_t stream) {
    const int*   wf      = (const int*)  d_in[0];
    const int*   bf      = (const int*)  d_in[2];
    const float* stm     = (const float*)d_in[4];
    const float* table   = (const float*)d_in[5];
    const float* ft_bias = (const float*)d_in[6];
    const float* W1      = (const float*)d_in[7];
    const float* b1      = (const float*)d_in[8];
    const float* W2      = (const float*)d_in[9];
    const float* b2      = (const float*)d_in[10];
    const float* Wo      = (const float*)d_in[11];
    const float* bo      = (const float*)d_in[12];
    float*       out     = (float*)d_out;

    const int B = in_sizes[1];                 // 16384
    const int tbl_elems = in_sizes[5];         // 40960*256
    const int nrows = tbl_elems / 256;         // 40960
    const size_t qbytes = (size_t)tbl_elems;   // 1 byte per element
    const size_t need = qbytes + (size_t)nrows * sizeof(float);

    if (ws_size >= need) {
        uint*  qt     = (uint*)d_ws;
        float* scales = (float*)((char*)d_ws + qbytes);
        quantize_table_i8<<<(nrows + 3) / 4, 256, 0, stream>>>(table, qt, scales, nrows);
        nnue_i8_async<<<B / NB, 256, 0, stream>>>(
            wf, bf, stm, qt, scales, ft_bias, W1, b1, W2, b2, Wo, bo, out);
    } else {
        nnue_fused_kernel<<<B / 8, 256, 0, stream>>>(
            wf, bf, stm, table, ft_bias, W1, b1, W2, b2, Wo, bo, out);
    }
}

// Round 15
// 55.509 us; speedup vs baseline: 1.4140x; 1.1776x over previous
//
#include <hip/hip_runtime.h>

#define KFEAT 32
#define NB 8            // batch elements per block
#define APITCH 272      // floats per bag row in accs region

typedef _Float16 f16x8 __attribute__((ext_vector_type(8)));
typedef _Float16 f16x4 __attribute__((ext_vector_type(4)));
typedef float    f32x4 __attribute__((ext_vector_type(4)));

__device__ __forceinline__ float clip01(float v) {
    return fminf(fmaxf(v, 0.0f), 1.0f);
}

// ---- one-pass per-row absmax + int8 quantize (one wave per row) ----
__global__ __launch_bounds__(256) void quantize_table_i8(
    const float* __restrict__ src, uint* __restrict__ qt,
    float* __restrict__ scales, int nrows)
{
    const int row = blockIdx.x * 4 + (threadIdx.x >> 6);
    const int l   = threadIdx.x & 63;
    if (row >= nrows) return;

    const float4 v = reinterpret_cast<const float4*>(src)[(size_t)row * 64 + l];
    float m = fmaxf(fmaxf(fabsf(v.x), fabsf(v.y)), fmaxf(fabsf(v.z), fabsf(v.w)));
    m = fmaxf(m, __shfl_xor(m, 1));
    m = fmaxf(m, __shfl_xor(m, 2));
    m = fmaxf(m, __shfl_xor(m, 4));
    m = fmaxf(m, __shfl_xor(m, 8));
    m = fmaxf(m, __shfl_xor(m, 16));
    m = fmaxf(m, __shfl_xor(m, 32));

    const float inv = (m > 0.0f) ? 127.0f / m : 0.0f;
    const int b0 = ((int)rintf(v.x * inv)) & 0xFF;
    const int b1 = ((int)rintf(v.y * inv)) & 0xFF;
    const int b2 = ((int)rintf(v.z * inv)) & 0xFF;
    const int b3 = ((int)rintf(v.w * inv)) & 0xFF;
    qt[(size_t)row * 64 + l] = (uint)b0 | ((uint)b1 << 8) | ((uint)b2 << 16) | ((uint)b3 << 24);
    if (l == 0) scales[row] = m * (1.0f / 127.0f);
}

// ---- W1 fp32 -> f16 (tiny, 16384 elements) ----
__global__ __launch_bounds__(256) void convert_w1_f16(
    const float* __restrict__ W1, _Float16* __restrict__ W1h, int n)
{
    const int i = blockIdx.x * 256 + threadIdx.x;
    if (i < n) W1h[i] = (_Float16)W1[i];
}

// ---------------- main fused kernel: int8 gather (R8) + MFMA layer-1 ----------------
__global__ __launch_bounds__(256, 8) void nnue_i8_mfma(
    const int* __restrict__ wf, const int* __restrict__ bf,
    const float* __restrict__ stm, const uint* __restrict__ qt,
    const float* __restrict__ scales,
    const _Float16* __restrict__ W1h,
    const float* __restrict__ ft_bias,
    const float* __restrict__ b1,
    const float* __restrict__ W2, const float* __restrict__ b2,
    const float* __restrict__ Wo, const float* __restrict__ bo,
    float* __restrict__ out)
{
    // Region: Phase A/B use it as accs[16][APITCH] f32 (17408B);
    // Phase B overlays xh[16 rows][512 k] f16 (16384B, rows 8-15 zero-padded).
    __shared__ float lds[16 * APITCH];
    __shared__ float y1s[NB][32];
    __shared__ f32x4 cred[2][64];       // cross-khalf MFMA partials

    char* xhb = reinterpret_cast<char*>(lds);

    const int t   = threadIdx.x;
    const int l   = t & 63;
    const int w   = t >> 6;     // wave 0..3
    const int sub = l & 31;
    const int b0  = blockIdx.x * NB;

    // ---- Phase A (R8, proven): 4 bags/wave; one 256B int8 row per wave-load ----
    {
        const int side = w & 1;
        const int eb   = w >> 1;
        const int* fp  = side ? bf : wf;

        #pragma unroll
        for (int g = 0; g < 4; ++g) {
            const int bag = g * 4 + w;                      // 0..15
            const int iv  = fp[(size_t)(b0 + 2 * g + eb) * KFEAT + sub];
            float a0 = 0.f, a1 = 0.f, a2 = 0.f, a3 = 0.f;
            #pragma unroll
            for (int k = 0; k < KFEAT; ++k) {
                const int row  = __builtin_amdgcn_readlane(iv, k);   // SGPR-uniform
                const int  q   = (int)qt[(size_t)row * 64 + l];
                const float sc = scales[row];                        // scalar load
                a0 = fmaf((float)((q << 24) >> 24), sc, a0);
                a1 = fmaf((float)((q << 16) >> 24), sc, a1);
                a2 = fmaf((float)((q <<  8) >> 24), sc, a2);
                a3 = fmaf((float)( q        >> 24), sc, a3);
            }
            *reinterpret_cast<float4*>(&lds[bag * APITCH + l * 4]) =
                make_float4(a0, a1, a2, a3);
        }
    }
    __syncthreads();

    // ---- Phase B: mix + clip -> f16 xh overlay (A-fragment layout, XOR swizzle) ----
    {
        const int e = t >> 5, r = t & 31;
        const float s  = stm[b0 + e];
        const float os = 1.0f - s;
        const float4 wa0 = *reinterpret_cast<const float4*>(&lds[(2 * e + 0) * APITCH + 4 * r]);
        const float4 ba0 = *reinterpret_cast<const float4*>(&lds[(2 * e + 1) * APITCH + 4 * r]);
        const float4 wa1 = *reinterpret_cast<const float4*>(&lds[(2 * e + 0) * APITCH + 4 * (r + 32)]);
        const float4 ba1 = *reinterpret_cast<const float4*>(&lds[(2 * e + 1) * APITCH + 4 * (r + 32)]);
        const float4 fb0 = reinterpret_cast<const float4*>(ft_bias)[r];
        const float4 fb1 = reinterpret_cast<const float4*>(ft_bias)[r + 32];
        __syncthreads();

        const int eswz = e << 3;    // (e&7)<<3; e<8

        // k = hf*256 + 4*i; byte addr = e*1024 + ((k ^ eswz) << 1)
        #define MIXW(wa, ba, fb, i, hf)                                              \
        {                                                                            \
            float4 xv;                                                               \
            if (hf == 0) {                                                           \
                xv.x = clip01(fmaf(s, (wa).x, fmaf(os, (ba).x, (fb).x)));            \
                xv.y = clip01(fmaf(s, (wa).y, fmaf(os, (ba).y, (fb).y)));            \
                xv.z = clip01(fmaf(s, (wa).z, fmaf(os, (ba).z, (fb).z)));            \
                xv.w = clip01(fmaf(s, (wa).w, fmaf(os, (ba).w, (fb).w)));            \
            } else {                                                                 \
                xv.x = clip01(fmaf(s, (ba).x, fmaf(os, (wa).x, (fb).x)));            \
                xv.y = clip01(fmaf(s, (ba).y, fmaf(os, (wa).y, (fb).y)));            \
                xv.z = clip01(fmaf(s, (ba).z, fmaf(os, (wa).z, (fb).z)));            \
                xv.w = clip01(fmaf(s, (ba).w, fmaf(os, (wa).w, (fb).w)));            \
            }                                                                        \
            const int k_ = (hf) * 256 + 4 * (i);                                     \
            f16x4 hv;                                                                \
            hv[0] = (_Float16)xv.x; hv[1] = (_Float16)xv.y;                          \
            hv[2] = (_Float16)xv.z; hv[3] = (_Float16)xv.w;                          \
            *reinterpret_cast<f16x4*>(xhb + e * 1024 + ((k_ ^ eswz) << 1)) = hv;     \
        }
        MIXW(wa0, ba0, fb0, r,      0)
        MIXW(wa1, ba1, fb1, r + 32, 0)
        MIXW(wa0, ba0, fb0, r,      1)
        MIXW(wa1, ba1, fb1, r + 32, 1)
        #undef MIXW

        // zero-pad rows 8..15 (bytes [8192,16384))
        *reinterpret_cast<uint4*>(xhb + 8192 + t * 32)      = make_uint4(0, 0, 0, 0);
        *reinterpret_cast<uint4*>(xhb + 8192 + t * 32 + 16) = make_uint4(0, 0, 0, 0);
    }
    __syncthreads();

    // ---- Phase C: layer 1 via MFMA. Y[16x32] = X[16x512] @ W1^T.
    // wave (ntile=w&1, khalf=w>>1): 8 x mfma_f32_16x16x32_f16 over its K-half.
    {
        const int ntile = w & 1;
        const int khalf = w >> 1;
        const int col   = l & 15;       // B col / A row / C col
        const int krow  = l >> 4;       // k-subgroup 0..3
        const int neuron = ntile * 16 + col;
        const int rswz   = (col & 7) << 3;

        f32x4 acc = {0.f, 0.f, 0.f, 0.f};
        const _Float16* bp = W1h + neuron * 512 + khalf * 256 + krow * 8;

        #pragma unroll
        for (int s = 0; s < 8; ++s) {
            const int k = khalf * 256 + s * 32 + krow * 8;
            const f16x8 a = *reinterpret_cast<const f16x8*>(
                xhb + col * 1024 + ((k ^ rswz) << 1));
            const f16x8 b = *reinterpret_cast<const f16x8*>(bp + s * 32);
            acc = __builtin_amdgcn_mfma_f32_16x16x32_f16(a, b, acc, 0, 0, 0);
        }

        if (khalf == 1) cred[ntile][l] = acc;
        __syncthreads();
        if (khalf == 0) {
            const f32x4 o = cred[ntile][l];
            const float bn = b1[neuron];
            if (krow < 2) {     // rows 0..7 are real elements
                #pragma unroll
                for (int reg = 0; reg < 4; ++reg) {
                    const int r8 = krow * 4 + reg;
                    y1s[r8][neuron] = clip01(acc[reg] + o[reg] + bn);
                }
            }
        }
    }
    __syncthreads();

    // ---- Phase D: layer 2 (32 -> 32) + output head; thread = (element, neuron) ----
    {
        const int e = t >> 5, i = t & 31;
        const float4* w2p = reinterpret_cast<const float4*>(W2 + i * 32);
        float a2 = b2[i];
        #pragma unroll
        for (int kq = 0; kq < 8; ++kq) {
            const float4 wq = w2p[kq];
            const float4 yq = *reinterpret_cast<const float4*>(&y1s[e][kq * 4]);
            a2 = fmaf(wq.x, yq.x, a2); a2 = fmaf(wq.y, yq.y, a2);
            a2 = fmaf(wq.z, yq.z, a2); a2 = fmaf(wq.w, yq.w, a2);
        }
        a2 = clip01(a2);
        float p = a2 * Wo[i];
        p += __shfl_xor(p, 1);  p += __shfl_xor(p, 2);
        p += __shfl_xor(p, 4);  p += __shfl_xor(p, 8);
        p += __shfl_xor(p, 16);
        if (i == 0) out[b0 + e] = p + bo[0];
    }
}

// ---------------- fallback: fp32 table path (if ws too small) ----------------
__global__ __launch_bounds__(256, 6) void nnue_fused_kernel(
    const int* __restrict__ wf, const int* __restrict__ bf,
    const float* __restrict__ stm, const float* __restrict__ table,
    const float* __restrict__ ft_bias,
    const float* __restrict__ W1, const float* __restrict__ b1,
    const float* __restrict__ W2, const float* __restrict__ b2,
    const float* __restrict__ Wo, const float* __restrict__ bo,
    float* __restrict__ out)
{
    __shared__ float4 accs[4][64];
    __shared__ float  xs[2 * 4 * 132];
    __shared__ float  y1s[2][32];

    const int t    = threadIdx.x;
    const int l    = t & 63;
    const int w    = t >> 6;
    const int side = w & 1;
    const int esub = w >> 1;

    const float4 ftb4 = reinterpret_cast<const float4*>(ft_bias)[l];
    const int*   fptr = side ? bf : wf;

    const int j = t >> 3;
    const int c = t & 7;
    const float* w1p = W1 + j * 512 + c * 64;
    const float* x0p = &xs[(0 * 4 + (c >> 1)) * 132 + (c & 1) * 64];
    const float* x1p = &xs[(1 * 4 + (c >> 1)) * 132 + (c & 1) * 64];

    for (int it = 0; it < 8 / 2; ++it) {
        const int b0 = blockIdx.x * 8 + it * 2;

        int idxv = fptr[(size_t)(b0 + esub) * KFEAT + (l & 31)];
        float4 acc = ftb4;
        #pragma unroll
        for (int k = 0; k < KFEAT; ++k) {
            const int row = __builtin_amdgcn_readlane(idxv, k);
            const float4 v = reinterpret_cast<const float4*>(table)[(size_t)row * 64 + l];
            acc.x += v.x; acc.y += v.y; acc.z += v.z; acc.w += v.w;
        }
        accs[w][l] = acc;
        __syncthreads();

        {
            const int e  = t >> 7;
            const int hf = (t >> 6) & 1;
            const int i  = t & 63;
            const float s  = stm[b0 + e];
            const float os = 1.0f - s;
            const float4 wa = accs[e * 2 + 0][i];
            const float4 ba = accs[e * 2 + 1][i];
            float4 x;
            if (hf == 0) {
                x.x = clip01(s * wa.x + os * ba.x);
                x.y = clip01(s * wa.y + os * ba.y);
                x.z = clip01(s * wa.z + os * ba.z);
                x.w = clip01(s * wa.w + os * ba.w);
            } else {
                x.x = clip01(s * ba.x + os * wa.x);
                x.y = clip01(s * ba.y + os * wa.y);
                x.z = clip01(s * ba.z + os * wa.z);
                x.w = clip01(s * ba.w + os * wa.w);
            }
            const int slot = hf * 64 + i;
            const int g = slot >> 5, i4 = slot & 31;
            *reinterpret_cast<float4*>(&xs[(e * 4 + g) * 132 + i4 * 4]) = x;
        }
        __syncthreads();

        float a0 = 0.0f, a1 = 0.0f;
        #pragma unroll 16
        for (int ii = 0; ii < 64; ++ii) {
            const float wv = w1p[ii];
            a0 = fmaf(wv, x0p[ii], a0);
            a1 = fmaf(wv, x1p[ii], a1);
        }
        a0 += __shfl_xor(a0, 1); a0 += __shfl_xor(a0, 2); a0 += __shfl_xor(a0, 4);
        a1 += __shfl_xor(a1, 1); a1 += __shfl_xor(a1, 2); a1 += __shfl_xor(a1, 4);
        if (c == 0) {
            const float bj = b1[j];
            y1s[0][j] = clip01(a0 + bj);
            y1s[1][j] = clip01(a1 + bj);
        }
        __syncthreads();

        if (t < 64) {
            const int e = t >> 5, i = t & 31;
            float a2 = b2[i];
            #pragma unroll
            for (int k2 = 0; k2 < 32; ++k2)
                a2 = fmaf(y1s[e][k2], W2[i * 32 + k2], a2);
            a2 = clip01(a2);
            float p = a2 * Wo[i];
            p += __shfl_xor(p, 1);  p += __shfl_xor(p, 2);
            p += __shfl_xor(p, 4);  p += __shfl_xor(p, 8);
            p += __shfl_xor(p, 16);
            if (i == 0) out[b0 + e] = p + bo[0];
        }
        __syncthreads();
    }
}

extern "C" void kernel_launch(void* const* d_in, const int* in_sizes, int n_in,
                              void* d_out, int out_size, void* d_ws, size_t ws_size,
                              hipStream_t stream) {
    const int*   wf      = (const int*)  d_in[0];
    const int*   bf      = (const int*)  d_in[2];
    const float* stm     = (const float*)d_in[4];
    const float* table   = (const float*)d_in[5];
    const float* ft_bias = (const float*)d_in[6];
    const float* W1      = (const float*)d_in[7];
    const float* b1      = (const float*)d_in[8];
    const float* W2      = (const float*)d_in[9];
    const float* b2      = (const float*)d_in[10];
    const float* Wo      = (const float*)d_in[11];
    const float* bo      = (const float*)d_in[12];
    float*       out     = (float*)d_out;

    const int B = in_sizes[1];                 // 16384
    const int tbl_elems = in_sizes[5];         // 40960*256
    const int nrows = tbl_elems / 256;         // 40960
    const int w1_elems = in_sizes[7];          // 32*512
    const size_t qbytes = (size_t)tbl_elems;   // 1 byte per element
    const size_t sbytes = (size_t)nrows * sizeof(float);
    const size_t hbytes = (size_t)w1_elems * sizeof(_Float16);
    const size_t need = qbytes + sbytes + hbytes;

    if (ws_size >= need) {
        uint*      qt     = (uint*)d_ws;
        float*     scales = (float*)((char*)d_ws + qbytes);
        _Float16*  W1h    = (_Float16*)((char*)d_ws + qbytes + sbytes);
        quantize_table_i8<<<(nrows + 3) / 4, 256, 0, stream>>>(table, qt, scales, nrows);
        convert_w1_f16<<<(w1_elems + 255) / 256, 256, 0, stream>>>(W1, W1h, w1_elems);
        nnue_i8_mfma<<<B / NB, 256, 0, stream>>>(
            wf, bf, stm, qt, scales, W1h, ft_bias, b1, W2, b2, Wo, bo, out);
    } else {
        nnue_fused_kernel<<<B / 8, 256, 0, stream>>>(
            wf, bf, stm, table, ft_bias, W1, b1, W2, b2, Wo, bo, out);
    }
}

// Round 16
// 52.905 us; speedup vs baseline: 1.4836x; 1.0492x over previous
//
#include <hip/hip_runtime.h>

#define KFEAT 32
#define NB 16           // batch elements per block (fills the 16-row MFMA tile)
#define APITCH 276      // floats per bag row (276 mod 32 = 20 -> bank-spread reads)

typedef _Float16 f16x8 __attribute__((ext_vector_type(8)));
typedef _Float16 f16x4 __attribute__((ext_vector_type(4)));
typedef float    f32x4 __attribute__((ext_vector_type(4)));

__device__ __forceinline__ float clip01(float v) {
    return fminf(fmaxf(v, 0.0f), 1.0f);
}

// ---- prep: per-row absmax + int8 quantize (one wave per row) + W1->f16 tail ----
__global__ __launch_bounds__(256) void prep_kernel(
    const float* __restrict__ src, uint* __restrict__ qt,
    float* __restrict__ scales, int nrows,
    const float* __restrict__ W1, _Float16* __restrict__ W1h, int w1n)
{
    const int qblocks = nrows / 4;
    if ((int)blockIdx.x < qblocks) {
        const int row = blockIdx.x * 4 + (threadIdx.x >> 6);
        const int l   = threadIdx.x & 63;

        const float4 v = reinterpret_cast<const float4*>(src)[(size_t)row * 64 + l];
        float m = fmaxf(fmaxf(fabsf(v.x), fabsf(v.y)), fmaxf(fabsf(v.z), fabsf(v.w)));
        m = fmaxf(m, __shfl_xor(m, 1));
        m = fmaxf(m, __shfl_xor(m, 2));
        m = fmaxf(m, __shfl_xor(m, 4));
        m = fmaxf(m, __shfl_xor(m, 8));
        m = fmaxf(m, __shfl_xor(m, 16));
        m = fmaxf(m, __shfl_xor(m, 32));

        const float inv = (m > 0.0f) ? 127.0f / m : 0.0f;
        const int b0 = ((int)rintf(v.x * inv)) & 0xFF;
        const int b1 = ((int)rintf(v.y * inv)) & 0xFF;
        const int b2 = ((int)rintf(v.z * inv)) & 0xFF;
        const int b3 = ((int)rintf(v.w * inv)) & 0xFF;
        qt[(size_t)row * 64 + l] = (uint)b0 | ((uint)b1 << 8) | ((uint)b2 << 16) | ((uint)b3 << 24);
        if (l == 0) scales[row] = m * (1.0f / 127.0f);
    } else {
        const int i = ((int)blockIdx.x - qblocks) * 256 + (int)threadIdx.x;
        if (i < w1n) W1h[i] = (_Float16)W1[i];
    }
}

// ---------------- main fused kernel: int8 gather + full-tile MFMA layer-1 ----------------
__global__ __launch_bounds__(256, 4) void nnue_i8_mfma(
    const int* __restrict__ wf, const int* __restrict__ bf,
    const float* __restrict__ stm, const uint* __restrict__ qt,
    const float* __restrict__ scales,
    const _Float16* __restrict__ W1h,
    const float* __restrict__ ft_bias,
    const float* __restrict__ b1,
    const float* __restrict__ W2, const float* __restrict__ b2,
    const float* __restrict__ Wo, const float* __restrict__ bo,
    float* __restrict__ out)
{
    // Region: Phase A/B use accs[32][APITCH] f32 (35328B);
    // Phase B overlays xh[16 rows][512 k] f16 (16384B, ALL rows real).
    __shared__ float lds[32 * APITCH];
    __shared__ float y1s[NB][32];
    __shared__ f32x4 cred[2][64];       // cross-khalf MFMA partials

    char* xhb = reinterpret_cast<char*>(lds);

    const int t   = threadIdx.x;
    const int l   = t & 63;
    const int w   = t >> 6;     // wave 0..3
    const int sub = l & 31;
    const int b0  = blockIdx.x * NB;

    // ---- Phase A (R8-proven): 8 bags/wave; one 256B int8 row per wave-load ----
    {
        const int side = w & 1;            // bag = g*4+w -> bag&1 == w&1
        const int eb   = w >> 1;
        const int* fp  = side ? bf : wf;

        #pragma unroll
        for (int g = 0; g < 8; ++g) {
            const int bag = g * 4 + w;                      // 0..31
            const int iv  = fp[(size_t)(b0 + 2 * g + eb) * KFEAT + sub];
            float a0 = 0.f, a1 = 0.f, a2 = 0.f, a3 = 0.f;
            #pragma unroll
            for (int k = 0; k < KFEAT; ++k) {
                const int row  = __builtin_amdgcn_readlane(iv, k);   // SGPR-uniform
                const int  q   = (int)qt[(size_t)row * 64 + l];
                const float sc = scales[row];                        // scalar load
                a0 = fmaf((float)((q << 24) >> 24), sc, a0);
                a1 = fmaf((float)((q << 16) >> 24), sc, a1);
                a2 = fmaf((float)((q <<  8) >> 24), sc, a2);
                a3 = fmaf((float)( q        >> 24), sc, a3);
            }
            *reinterpret_cast<float4*>(&lds[bag * APITCH + l * 4]) =
                make_float4(a0, a1, a2, a3);
        }
    }
    __syncthreads();

    // ---- Phase B: mix + clip -> f16 xh overlay (A-fragment layout, XOR swizzle) ----
    {
        const int e = t >> 4;       // element 0..15
        const int r = t & 15;       // dim-chunk lane 0..15
        const float s  = stm[b0 + e];
        const float os = 1.0f - s;

        float4 wa[4], ba[4], fb[4];
        #pragma unroll
        for (int q = 0; q < 4; ++q) {
            const int c4 = r + 16 * q;   // float4 index 0..63 of the 256-dim half
            wa[q] = *reinterpret_cast<const float4*>(&lds[(2 * e + 0) * APITCH + 4 * c4]);
            ba[q] = *reinterpret_cast<const float4*>(&lds[(2 * e + 1) * APITCH + 4 * c4]);
            fb[q] = reinterpret_cast<const float4*>(ft_bias)[c4];
        }
        __syncthreads();

        const int eswz = (e & 7) << 3;

        #pragma unroll
        for (int q = 0; q < 4; ++q) {
            const int c4 = r + 16 * q;
            float4 x0, x1;
            x0.x = clip01(fmaf(s, wa[q].x, fmaf(os, ba[q].x, fb[q].x)));
            x0.y = clip01(fmaf(s, wa[q].y, fmaf(os, ba[q].y, fb[q].y)));
            x0.z = clip01(fmaf(s, wa[q].z, fmaf(os, ba[q].z, fb[q].z)));
            x0.w = clip01(fmaf(s, wa[q].w, fmaf(os, ba[q].w, fb[q].w)));
            x1.x = clip01(fmaf(s, ba[q].x, fmaf(os, wa[q].x, fb[q].x)));
            x1.y = clip01(fmaf(s, ba[q].y, fmaf(os, wa[q].y, fb[q].y)));
            x1.z = clip01(fmaf(s, ba[q].z, fmaf(os, wa[q].z, fb[q].z)));
            x1.w = clip01(fmaf(s, ba[q].w, fmaf(os, wa[q].w, fb[q].w)));
            const int k0 = 4 * c4;           // wtm half: dims 0..255
            const int k1 = 256 + 4 * c4;     // btm half: dims 256..511
            f16x4 h0, h1;
            h0[0] = (_Float16)x0.x; h0[1] = (_Float16)x0.y;
            h0[2] = (_Float16)x0.z; h0[3] = (_Float16)x0.w;
            h1[0] = (_Float16)x1.x; h1[1] = (_Float16)x1.y;
            h1[2] = (_Float16)x1.z; h1[3] = (_Float16)x1.w;
            *reinterpret_cast<f16x4*>(xhb + e * 1024 + ((k0 ^ eswz) << 1)) = h0;
            *reinterpret_cast<f16x4*>(xhb + e * 1024 + ((k1 ^ eswz) << 1)) = h1;
        }
    }
    __syncthreads();

    // ---- Phase C: layer 1 via MFMA. Y[16x32] = X[16x512] @ W1^T; all 16 rows real.
    {
        const int ntile = w & 1;
        const int khalf = w >> 1;
        const int col   = l & 15;       // B col / A row / C col
        const int krow  = l >> 4;       // k-subgroup 0..3
        const int neuron = ntile * 16 + col;
        const int rswz   = (col & 7) << 3;

        f32x4 acc = {0.f, 0.f, 0.f, 0.f};
        const _Float16* bp = W1h + neuron * 512 + khalf * 256 + krow * 8;

        #pragma unroll
        for (int s = 0; s < 8; ++s) {
            const int k = khalf * 256 + s * 32 + krow * 8;
            const f16x8 a = *reinterpret_cast<const f16x8*>(
                xhb + col * 1024 + ((k ^ rswz) << 1));
            const f16x8 b = *reinterpret_cast<const f16x8*>(bp + s * 32);
            acc = __builtin_amdgcn_mfma_f32_16x16x32_f16(a, b, acc, 0, 0, 0);
        }

        if (khalf == 1) cred[ntile][l] = acc;
        __syncthreads();
        if (khalf == 0) {
            const f32x4 o = cred[ntile][l];
            const float bn = b1[neuron];
            #pragma unroll
            for (int reg = 0; reg < 4; ++reg) {
                const int r16 = krow * 4 + reg;     // C row = element, all real
                y1s[r16][neuron] = clip01(acc[reg] + o[reg] + bn);
            }
        }
    }
    __syncthreads();

    // ---- Phase D: layer 2 (32 -> 32) + output head; two elements per thread-slot ----
    {
        const int i = t & 31;
        const float4* w2p = reinterpret_cast<const float4*>(W2 + i * 32);
        #pragma unroll
        for (int half = 0; half < 2; ++half) {
            const int e = (t >> 5) + half * 8;
            float a2 = b2[i];
            #pragma unroll
            for (int kq = 0; kq < 8; ++kq) {
                const float4 wq = w2p[kq];
                const float4 yq = *reinterpret_cast<const float4*>(&y1s[e][kq * 4]);
                a2 = fmaf(wq.x, yq.x, a2); a2 = fmaf(wq.y, yq.y, a2);
                a2 = fmaf(wq.z, yq.z, a2); a2 = fmaf(wq.w, yq.w, a2);
            }
            a2 = clip01(a2);
            float p = a2 * Wo[i];
            p += __shfl_xor(p, 1);  p += __shfl_xor(p, 2);
            p += __shfl_xor(p, 4);  p += __shfl_xor(p, 8);
            p += __shfl_xor(p, 16);
            if (i == 0) out[b0 + e] = p + bo[0];
        }
    }
}

// ---------------- fallback: fp32 table path (if ws too small) ----------------
__global__ __launch_bounds__(256, 6) void nnue_fused_kernel(
    const int* __restrict__ wf, const int* __restrict__ bf,
    const float* __restrict__ stm, const float* __restrict__ table,
    const float* __restrict__ ft_bias,
    const float* __restrict__ W1, const float* __restrict__ b1,
    const float* __restrict__ W2, const float* __restrict__ b2,
    const float* __restrict__ Wo, const float* __restrict__ bo,
    float* __restrict__ out)
{
    __shared__ float4 accs[4][64];
    __shared__ float  xs[2 * 4 * 132];
    __shared__ float  y1s[2][32];

    const int t    = threadIdx.x;
    const int l    = t & 63;
    const int w    = t >> 6;
    const int side = w & 1;
    const int esub = w >> 1;

    const float4 ftb4 = reinterpret_cast<const float4*>(ft_bias)[l];
    const int*   fptr = side ? bf : wf;

    const int j = t >> 3;
    const int c = t & 7;
    const float* w1p = W1 + j * 512 + c * 64;
    const float* x0p = &xs[(0 * 4 + (c >> 1)) * 132 + (c & 1) * 64];
    const float* x1p = &xs[(1 * 4 + (c >> 1)) * 132 + (c & 1) * 64];

    for (int it = 0; it < 8 / 2; ++it) {
        const int b0 = blockIdx.x * 8 + it * 2;

        int idxv = fptr[(size_t)(b0 + esub) * KFEAT + (l & 31)];
        float4 acc = ftb4;
        #pragma unroll
        for (int k = 0; k < KFEAT; ++k) {
            const int row = __builtin_amdgcn_readlane(idxv, k);
            const float4 v = reinterpret_cast<const float4*>(table)[(size_t)row * 64 + l];
            acc.x += v.x; acc.y += v.y; acc.z += v.z; acc.w += v.w;
        }
        accs[w][l] = acc;
        __syncthreads();

        {
            const int e  = t >> 7;
            const int hf = (t >> 6) & 1;
            const int i  = t & 63;
            const float s  = stm[b0 + e];
            const float os = 1.0f - s;
            const float4 wa = accs[e * 2 + 0][i];
            const float4 ba = accs[e * 2 + 1][i];
            float4 x;
            if (hf == 0) {
                x.x = clip01(s * wa.x + os * ba.x);
                x.y = clip01(s * wa.y + os * ba.y);
                x.z = clip01(s * wa.z + os * ba.z);
                x.w = clip01(s * wa.w + os * ba.w);
            } else {
                x.x = clip01(s * ba.x + os * wa.x);
                x.y = clip01(s * ba.y + os * wa.y);
                x.z = clip01(s * ba.z + os * wa.z);
                x.w = clip01(s * ba.w + os * wa.w);
            }
            const int slot = hf * 64 + i;
            const int g = slot >> 5, i4 = slot & 31;
            *reinterpret_cast<float4*>(&xs[(e * 4 + g) * 132 + i4 * 4]) = x;
        }
        __syncthreads();

        float a0 = 0.0f, a1 = 0.0f;
        #pragma unroll 16
        for (int ii = 0; ii < 64; ++ii) {
            const float wv = w1p[ii];
            a0 = fmaf(wv, x0p[ii], a0);
            a1 = fmaf(wv, x1p[ii], a1);
        }
        a0 += __shfl_xor(a0, 1); a0 += __shfl_xor(a0, 2); a0 += __shfl_xor(a0, 4);
        a1 += __shfl_xor(a1, 1); a1 += __shfl_xor(a1, 2); a1 += __shfl_xor(a1, 4);
        if (c == 0) {
            const float bj = b1[j];
            y1s[0][j] = clip01(a0 + bj);
            y1s[1][j] = clip01(a1 + bj);
        }
        __syncthreads();

        if (t < 64) {
            const int e = t >> 5, i = t & 31;
            float a2 = b2[i];
            #pragma unroll
            for (int k2 = 0; k2 < 32; ++k2)
                a2 = fmaf(y1s[e][k2], W2[i * 32 + k2], a2);
            a2 = clip01(a2);
            float p = a2 * Wo[i];
            p += __shfl_xor(p, 1);  p += __shfl_xor(p, 2);
            p += __shfl_xor(p, 4);  p += __shfl_xor(p, 8);
            p += __shfl_xor(p, 16);
            if (i == 0) out[b0 + e] = p + bo[0];
        }
        __syncthreads();
    }
}

extern "C" void kernel_launch(void* const* d_in, const int* in_sizes, int n_in,
                              void* d_out, int out_size, void* d_ws, size_t ws_size,
                              hipStream_t stream) {
    const int*   wf      = (const int*)  d_in[0];
    const int*   bf      = (const int*)  d_in[2];
    const float* stm     = (const float*)d_in[4];
    const float* table   = (const float*)d_in[5];
    const float* ft_bias = (const float*)d_in[6];
    const float* W1      = (const float*)d_in[7];
    const float* b1      = (const float*)d_in[8];
    const float* W2      = (const float*)d_in[9];
    const float* b2      = (const float*)d_in[10];
    const float* Wo      = (const float*)d_in[11];
    const float* bo      = (const float*)d_in[12];
    float*       out     = (float*)d_out;

    const int B = in_sizes[1];                 // 16384
    const int tbl_elems = in_sizes[5];         // 40960*256
    const int nrows = tbl_elems / 256;         // 40960
    const int w1_elems = in_sizes[7];          // 32*512
    const size_t qbytes = (size_t)tbl_elems;   // 1 byte per element
    const size_t sbytes = (size_t)nrows * sizeof(float);
    const size_t hbytes = (size_t)w1_elems * sizeof(_Float16);
    const size_t need = qbytes + sbytes + hbytes;

    if (ws_size >= need) {
        uint*      qt     = (uint*)d_ws;
        float*     scales = (float*)((char*)d_ws + qbytes);
        _Float16*  W1h    = (_Float16*)((char*)d_ws + qbytes + sbytes);
        const int grid = nrows / 4 + (w1_elems + 255) / 256;
        prep_kernel<<<grid, 256, 0, stream>>>(table, qt, scales, nrows, W1, W1h, w1_elems);
        nnue_i8_mfma<<<B / NB, 256, 0, stream>>>(
            wf, bf, stm, qt, scales, W1h, ft_bias, b1, W2, b2, Wo, bo, out);
    } else {
        nnue_fused_kernel<<<B / 8, 256, 0, stream>>>(
            wf, bf, stm, table, ft_bias, W1, b1, W2, b2, Wo, bo, out);
    }
}

// Round 17
// 51.650 us; speedup vs baseline: 1.5197x; 1.0243x over previous
//
#include <hip/hip_runtime.h>

#define KFEAT 32
#define NB 16           // batch elements per block (fills the 16-row MFMA tile)
#define APITCH 276      // floats per bag row (276 mod 32 = 20 -> bank-spread reads)

typedef _Float16 f16x8 __attribute__((ext_vector_type(8)));
typedef _Float16 f16x4 __attribute__((ext_vector_type(4)));
typedef float    f32x4 __attribute__((ext_vector_type(4)));

__device__ __forceinline__ float clip01(float v) {
    return fminf(fmaxf(v, 0.0f), 1.0f);
}

// ---- prep: per-row absmax + EXCESS-128 int8 quantize (one wave per row) + W1->f16 tail ----
__global__ __launch_bounds__(256) void prep_kernel(
    const float* __restrict__ src, uint* __restrict__ qt,
    float* __restrict__ scales, int nrows,
    const float* __restrict__ W1, _Float16* __restrict__ W1h, int w1n)
{
    const int qblocks = nrows / 4;
    if ((int)blockIdx.x < qblocks) {
        const int row = blockIdx.x * 4 + (threadIdx.x >> 6);
        const int l   = threadIdx.x & 63;

        const float4 v = reinterpret_cast<const float4*>(src)[(size_t)row * 64 + l];
        float m = fmaxf(fmaxf(fabsf(v.x), fabsf(v.y)), fmaxf(fabsf(v.z), fabsf(v.w)));
        m = fmaxf(m, __shfl_xor(m, 1));
        m = fmaxf(m, __shfl_xor(m, 2));
        m = fmaxf(m, __shfl_xor(m, 4));
        m = fmaxf(m, __shfl_xor(m, 8));
        m = fmaxf(m, __shfl_xor(m, 16));
        m = fmaxf(m, __shfl_xor(m, 32));

        const float inv = (m > 0.0f) ? 127.0f / m : 0.0f;
        // excess-128: stored byte = q + 128 (q in [-127,127] -> [1,255])
        const uint b0 = (uint)(((int)rintf(v.x * inv) + 128) & 0xFF);
        const uint b1 = (uint)(((int)rintf(v.y * inv) + 128) & 0xFF);
        const uint b2 = (uint)(((int)rintf(v.z * inv) + 128) & 0xFF);
        const uint b3 = (uint)(((int)rintf(v.w * inv) + 128) & 0xFF);
        qt[(size_t)row * 64 + l] = b0 | (b1 << 8) | (b2 << 16) | (b3 << 24);
        if (l == 0) scales[row] = m * (1.0f / 127.0f);
    } else {
        const int i = ((int)blockIdx.x - qblocks) * 256 + (int)threadIdx.x;
        if (i < w1n) W1h[i] = (_Float16)W1[i];
    }
}

// ---------------- main fused kernel: int8 gather + full-tile MFMA layer-1 ----------------
__global__ __launch_bounds__(256, 4) void nnue_i8_mfma(
    const int* __restrict__ wf, const int* __restrict__ bf,
    const float* __restrict__ stm, const uint* __restrict__ qt,
    const float* __restrict__ scales,
    const _Float16* __restrict__ W1h,
    const float* __restrict__ ft_bias,
    const float* __restrict__ b1,
    const float* __restrict__ W2, const float* __restrict__ b2,
    const float* __restrict__ Wo, const float* __restrict__ bo,
    float* __restrict__ out)
{
    // Region: Phase A/B use accs[32][APITCH] f32 (35328B);
    // Phase B overlays xh[16 rows][512 k] f16 (16384B, ALL rows real).
    __shared__ float lds[32 * APITCH];
    __shared__ float y1s[NB][32];
    __shared__ f32x4 cred[2][64];       // cross-khalf MFMA partials

    char* xhb = reinterpret_cast<char*>(lds);

    const int t   = threadIdx.x;
    const int l   = t & 63;
    const int w   = t >> 6;     // wave 0..3
    const int sub = l & 31;
    const int b0  = blockIdx.x * NB;

    // ---- Phase A: 8 bags/wave; one 256B int8 row per wave-load.
    // Dequant via v_cvt_f32_ubyte0..3 (excess-128) + exact -128*corr fixup.
    {
        const int side = w & 1;            // bag = g*4+w -> bag&1 == w&1
        const int eb   = w >> 1;
        const int* fp  = side ? bf : wf;

        int ivs[8];
        #pragma unroll
        for (int g = 0; g < 8; ++g)
            ivs[g] = fp[(size_t)(b0 + 2 * g + eb) * KFEAT + sub];

        #pragma unroll
        for (int g = 0; g < 8; ++g) {
            const int bag = g * 4 + w;                      // 0..31
            const int iv  = ivs[g];
            float a0 = 0.f, a1 = 0.f, a2 = 0.f, a3 = 0.f;
            float corr = 0.f;
            #pragma unroll
            for (int k = 0; k < KFEAT; ++k) {
                const int row  = __builtin_amdgcn_readlane(iv, k);   // SGPR-uniform
                const uint q   = qt[(size_t)row * 64 + l];
                const float sc = scales[row];                        // scalar load
                corr += sc;
                a0 = fmaf((float)(q & 0xFFu),         sc, a0);   // v_cvt_f32_ubyte0
                a1 = fmaf((float)((q >> 8) & 0xFFu),  sc, a1);   // v_cvt_f32_ubyte1
                a2 = fmaf((float)((q >> 16) & 0xFFu), sc, a2);   // v_cvt_f32_ubyte2
                a3 = fmaf((float)(q >> 24),           sc, a3);   // v_cvt_f32_ubyte3
            }
            const float c128 = -128.0f * corr;
            *reinterpret_cast<float4*>(&lds[bag * APITCH + l * 4]) =
                make_float4(a0 + c128, a1 + c128, a2 + c128, a3 + c128);
        }
    }
    __syncthreads();

    // ---- Phase B: mix + clip -> f16 xh overlay (A-fragment layout, XOR swizzle) ----
    {
        const int e = t >> 4;       // element 0..15
        const int r = t & 15;       // dim-chunk lane 0..15
        const float s  = stm[b0 + e];
        const float os = 1.0f - s;

        float4 wa[4], ba[4], fb[4];
        #pragma unroll
        for (int q = 0; q < 4; ++q) {
            const int c4 = r + 16 * q;   // float4 index 0..63 of the 256-dim half
            wa[q] = *reinterpret_cast<const float4*>(&lds[(2 * e + 0) * APITCH + 4 * c4]);
            ba[q] = *reinterpret_cast<const float4*>(&lds[(2 * e + 1) * APITCH + 4 * c4]);
            fb[q] = reinterpret_cast<const float4*>(ft_bias)[c4];
        }
        __syncthreads();

        const int eswz = (e & 7) << 3;

        #pragma unroll
        for (int q = 0; q < 4; ++q) {
            const int c4 = r + 16 * q;
            float4 x0, x1;
            x0.x = clip01(fmaf(s, wa[q].x, fmaf(os, ba[q].x, fb[q].x)));
            x0.y = clip01(fmaf(s, wa[q].y, fmaf(os, ba[q].y, fb[q].y)));
            x0.z = clip01(fmaf(s, wa[q].z, fmaf(os, ba[q].z, fb[q].z)));
            x0.w = clip01(fmaf(s, wa[q].w, fmaf(os, ba[q].w, fb[q].w)));
            x1.x = clip01(fmaf(s, ba[q].x, fmaf(os, wa[q].x, fb[q].x)));
            x1.y = clip01(fmaf(s, ba[q].y, fmaf(os, wa[q].y, fb[q].y)));
            x1.z = clip01(fmaf(s, ba[q].z, fmaf(os, wa[q].z, fb[q].z)));
            x1.w = clip01(fmaf(s, ba[q].w, fmaf(os, wa[q].w, fb[q].w)));
            const int k0 = 4 * c4;           // wtm half: dims 0..255
            const int k1 = 256 + 4 * c4;     // btm half: dims 256..511
            f16x4 h0, h1;
            h0[0] = (_Float16)x0.x; h0[1] = (_Float16)x0.y;
            h0[2] = (_Float16)x0.z; h0[3] = (_Float16)x0.w;
            h1[0] = (_Float16)x1.x; h1[1] = (_Float16)x1.y;
            h1[2] = (_Float16)x1.z; h1[3] = (_Float16)x1.w;
            *reinterpret_cast<f16x4*>(xhb + e * 1024 + ((k0 ^ eswz) << 1)) = h0;
            *reinterpret_cast<f16x4*>(xhb + e * 1024 + ((k1 ^ eswz) << 1)) = h1;
        }
    }
    __syncthreads();

    // ---- Phase C: layer 1 via MFMA. Y[16x32] = X[16x512] @ W1^T; all 16 rows real.
    {
        const int ntile = w & 1;
        const int khalf = w >> 1;
        const int col   = l & 15;       // B col / A row / C col
        const int krow  = l >> 4;       // k-subgroup 0..3
        const int neuron = ntile * 16 + col;
        const int rswz   = (col & 7) << 3;

        f32x4 acc = {0.f, 0.f, 0.f, 0.f};
        const _Float16* bp = W1h + neuron * 512 + khalf * 256 + krow * 8;

        #pragma unroll
        for (int s = 0; s < 8; ++s) {
            const int k = khalf * 256 + s * 32 + krow * 8;
            const f16x8 a = *reinterpret_cast<const f16x8*>(
                xhb + col * 1024 + ((k ^ rswz) << 1));
            const f16x8 b = *reinterpret_cast<const f16x8*>(bp + s * 32);
            acc = __builtin_amdgcn_mfma_f32_16x16x32_f16(a, b, acc, 0, 0, 0);
        }

        if (khalf == 1) cred[ntile][l] = acc;
        __syncthreads();
        if (khalf == 0) {
            const f32x4 o = cred[ntile][l];
            const float bn = b1[neuron];
            #pragma unroll
            for (int reg = 0; reg < 4; ++reg) {
                const int r16 = krow * 4 + reg;     // C row = element, all real
                y1s[r16][neuron] = clip01(acc[reg] + o[reg] + bn);
            }
        }
    }
    __syncthreads();

    // ---- Phase D: layer 2 (32 -> 32) + output head; two elements per thread-slot ----
    {
        const int i = t & 31;
        const float4* w2p = reinterpret_cast<const float4*>(W2 + i * 32);
        #pragma unroll
        for (int half = 0; half < 2; ++half) {
            const int e = (t >> 5) + half * 8;
            float a2 = b2[i];
            #pragma unroll
            for (int kq = 0; kq < 8; ++kq) {
                const float4 wq = w2p[kq];
                const float4 yq = *reinterpret_cast<const float4*>(&y1s[e][kq * 4]);
                a2 = fmaf(wq.x, yq.x, a2); a2 = fmaf(wq.y, yq.y, a2);
                a2 = fmaf(wq.z, yq.z, a2); a2 = fmaf(wq.w, yq.w, a2);
            }
            a2 = clip01(a2);
            float p = a2 * Wo[i];
            p += __shfl_xor(p, 1);  p += __shfl_xor(p, 2);
            p += __shfl_xor(p, 4);  p += __shfl_xor(p, 8);
            p += __shfl_xor(p, 16);
            if (i == 0) out[b0 + e] = p + bo[0];
        }
    }
}

// ---------------- fallback: fp32 table path (if ws too small) ----------------
__global__ __launch_bounds__(256, 6) void nnue_fused_kernel(
    const int* __restrict__ wf, const int* __restrict__ bf,
    const float* __restrict__ stm, const float* __restrict__ table,
    const float* __restrict__ ft_bias,
    const float* __restrict__ W1, const float* __restrict__ b1,
    const float* __restrict__ W2, const float* __restrict__ b2,
    const float* __restrict__ Wo, const float* __restrict__ bo,
    float* __restrict__ out)
{
    __shared__ float4 accs[4][64];
    __shared__ float  xs[2 * 4 * 132];
    __shared__ float  y1s[2][32];

    const int t    = threadIdx.x;
    const int l    = t & 63;
    const int w    = t >> 6;
    const int side = w & 1;
    const int esub = w >> 1;

    const float4 ftb4 = reinterpret_cast<const float4*>(ft_bias)[l];
    const int*   fptr = side ? bf : wf;

    const int j = t >> 3;
    const int c = t & 7;
    const float* w1p = W1 + j * 512 + c * 64;
    const float* x0p = &xs[(0 * 4 + (c >> 1)) * 132 + (c & 1) * 64];
    const float* x1p = &xs[(1 * 4 + (c >> 1)) * 132 + (c & 1) * 64];

    for (int it = 0; it < 8 / 2; ++it) {
        const int b0 = blockIdx.x * 8 + it * 2;

        int idxv = fptr[(size_t)(b0 + esub) * KFEAT + (l & 31)];
        float4 acc = ftb4;
        #pragma unroll
        for (int k = 0; k < KFEAT; ++k) {
            const int row = __builtin_amdgcn_readlane(idxv, k);
            const float4 v = reinterpret_cast<const float4*>(table)[(size_t)row * 64 + l];
            acc.x += v.x; acc.y += v.y; acc.z += v.z; acc.w += v.w;
        }
        accs[w][l] = acc;
        __syncthreads();

        {
            const int e  = t >> 7;
            const int hf = (t >> 6) & 1;
            const int i  = t & 63;
            const float s  = stm[b0 + e];
            const float os = 1.0f - s;
            const float4 wa = accs[e * 2 + 0][i];
            const float4 ba = accs[e * 2 + 1][i];
            float4 x;
            if (hf == 0) {
                x.x = clip01(s * wa.x + os * ba.x);
                x.y = clip01(s * wa.y + os * ba.y);
                x.z = clip01(s * wa.z + os * ba.z);
                x.w = clip01(s * wa.w + os * ba.w);
            } else {
                x.x = clip01(s * ba.x + os * wa.x);
                x.y = clip01(s * ba.y + os * wa.y);
                x.z = clip01(s * ba.z + os * wa.z);
                x.w = clip01(s * ba.w + os * wa.w);
            }
            const int slot = hf * 64 + i;
            const int g = slot >> 5, i4 = slot & 31;
            *reinterpret_cast<float4*>(&xs[(e * 4 + g) * 132 + i4 * 4]) = x;
        }
        __syncthreads();

        float a0 = 0.0f, a1 = 0.0f;
        #pragma unroll 16
        for (int ii = 0; ii < 64; ++ii) {
            const float wv = w1p[ii];
            a0 = fmaf(wv, x0p[ii], a0);
            a1 = fmaf(wv, x1p[ii], a1);
        }
        a0 += __shfl_xor(a0, 1); a0 += __shfl_xor(a0, 2); a0 += __shfl_xor(a0, 4);
        a1 += __shfl_xor(a1, 1); a1 += __shfl_xor(a1, 2); a1 += __shfl_xor(a1, 4);
        if (c == 0) {
            const float bj = b1[j];
            y1s[0][j] = clip01(a0 + bj);
            y1s[1][j] = clip01(a1 + bj);
        }
        __syncthreads();

        if (t < 64) {
            const int e = t >> 5, i = t & 31;
            float a2 = b2[i];
            #pragma unroll
            for (int k2 = 0; k2 < 32; ++k2)
                a2 = fmaf(y1s[e][k2], W2[i * 32 + k2], a2);
            a2 = clip01(a2);
            float p = a2 * Wo[i];
            p += __shfl_xor(p, 1);  p += __shfl_xor(p, 2);
            p += __shfl_xor(p, 4);  p += __shfl_xor(p, 8);
            p += __shfl_xor(p, 16);
            if (i == 0) out[b0 + e] = p + bo[0];
        }
        __syncthreads();
    }
}

extern "C" void kernel_launch(void* const* d_in, const int* in_sizes, int n_in,
                              void* d_out, int out_size, void* d_ws, size_t ws_size,
                              hipStream_t stream) {
    const int*   wf      = (const int*)  d_in[0];
    const int*   bf      = (const int*)  d_in[2];
    const float* stm     = (const float*)d_in[4];
    const float* table   = (const float*)d_in[5];
    const float* ft_bias = (const float*)d_in[6];
    const float* W1      = (const float*)d_in[7];
    const float* b1      = (const float*)d_in[8];
    const float* W2      = (const float*)d_in[9];
    const float* b2      = (const float*)d_in[10];
    const float* Wo      = (const float*)d_in[11];
    const float* bo      = (const float*)d_in[12];
    float*       out     = (float*)d_out;

    const int B = in_sizes[1];                 // 16384
    const int tbl_elems = in_sizes[5];         // 40960*256
    const int nrows = tbl_elems / 256;         // 40960
    const int w1_elems = in_sizes[7];          // 32*512
    const size_t qbytes = (size_t)tbl_elems;   // 1 byte per element
    const size_t sbytes = (size_t)nrows * sizeof(float);
    const size_t hbytes = (size_t)w1_elems * sizeof(_Float16);
    const size_t need = qbytes + sbytes + hbytes;

    if (ws_size >= need) {
        uint*      qt     = (uint*)d_ws;
        float*     scales = (float*)((char*)d_ws + qbytes);
        _Float16*  W1h    = (_Float16*)((char*)d_ws + qbytes + sbytes);
        const int grid = nrows / 4 + (w1_elems + 255) / 256;
        prep_kernel<<<grid, 256, 0, stream>>>(table, qt, scales, nrows, W1, W1h, w1_elems);
        nnue_i8_mfma<<<B / NB, 256, 0, stream>>>(
            wf, bf, stm, qt, scales, W1h, ft_bias, b1, W2, b2, Wo, bo, out);
    } else {
        nnue_fused_kernel<<<B / 8, 256, 0, stream>>>(
            wf, bf, stm, table, ft_bias, W1, b1, W2, b2, Wo, bo, out);
    }
}